// Round 1
// baseline (226.807 us; speedup 1.0000x reference)
//
#include <hip/hip_runtime.h>
#include <cstdint>

typedef __attribute__((ext_vector_type(8))) _Float16 f16x8;
typedef __attribute__((ext_vector_type(4))) float f32x4;

#define DEV static __device__ __forceinline__

DEV void gld_lds16(void* lds_base, const void* gsrc) {
  __builtin_amdgcn_global_load_lds(
      (const __attribute__((address_space(1))) unsigned int*)gsrc,
      (__attribute__((address_space(3))) unsigned int*)lds_base,
      16, 0, 0);
}
DEV unsigned short f2h(float f) {
  _Float16 h = (_Float16)f;
  return __builtin_bit_cast(unsigned short, h);
}
DEV float v_exp2(float x) { float r; asm("v_exp_f32 %0, %1" : "=v"(r) : "v"(x)); return r; }
DEV float v_rcp(float x) { float r; asm("v_rcp_f32 %0, %1" : "=v"(r) : "v"(x)); return r; }

// ---------------- geometry ----------------
// B=4, C=256, H=W=64, N=4096, heads=2, hd=128
// ws layout (bytes):
//   Xpad [4][74][74][256] f16 : 0        .. 11214848
//   Wq [3][3][256][256] f16   : 11214848 .. 12394496
//   Wk [256][256] f16         : 12394496 .. 12525568
//   Wv [256][256] f16         : 12525568 .. 12656640
//   Q  [8][4096][128] f16     : 12656640 .. 21045248   (pre-scaled by log2e/sqrt(128))
//   K  [8][4096][128] f16     : 21045248 .. 29433856
//   V  [8][128][4096] f16     : 29433856 .. 37822464

// ---------- prep: x (f32 NCHW) -> Xpad (f16, pixel-major, halo 5) ----------
__global__ __launch_bounds__(256) void k_prep_x(const float* __restrict__ x, char* __restrict__ xpad) {
  __shared__ float xs[32 * 257];
  int h = blockIdx.x, b = blockIdx.y, t = threadIdx.x;
  const float* xb = x + (size_t)b * 1048576 + h * 64;
  for (int half = 0; half < 2; half++) {
    int w0 = half * 32;
    for (int kk = 0; kk < 32; kk++) {
      int flat = kk * 256 + t;       // ci*32 + w
      int ci = flat >> 5, w = flat & 31;
      xs[w * 257 + ci] = xb[ci * 4096 + w0 + w];
    }
    __syncthreads();
    for (int g = 0; g < 4; g++) {
      int w = g * 8 + (t >> 5);
      int cg = t & 31;               // 8-ci chunk
      float v0 = xs[w * 257 + cg * 8 + 0], v1 = xs[w * 257 + cg * 8 + 1];
      float v2 = xs[w * 257 + cg * 8 + 2], v3 = xs[w * 257 + cg * 8 + 3];
      float v4 = xs[w * 257 + cg * 8 + 4], v5 = xs[w * 257 + cg * 8 + 5];
      float v6 = xs[w * 257 + cg * 8 + 6], v7 = xs[w * 257 + cg * 8 + 7];
      uint4 pk;
      pk.x = (unsigned)f2h(v0) | ((unsigned)f2h(v1) << 16);
      pk.y = (unsigned)f2h(v2) | ((unsigned)f2h(v3) << 16);
      pk.z = (unsigned)f2h(v4) | ((unsigned)f2h(v5) << 16);
      pk.w = (unsigned)f2h(v6) | ((unsigned)f2h(v7) << 16);
      *(uint4*)(xpad + ((size_t)((b * 74 + h + 5) * 74) + w0 + w + 5) * 512 + cg * 16) = pk;
    }
    __syncthreads();
  }
}

// ---------- prep: weights -> f16 ----------
__global__ __launch_bounds__(256) void k_prep_w(
    const float* __restrict__ qw, const float* __restrict__ kw, const float* __restrict__ vw,
    unsigned short* __restrict__ Wq, unsigned short* __restrict__ Wk, unsigned short* __restrict__ Wv) {
  int gid = blockIdx.x * 256 + threadIdx.x;   // co*256+ci
  const float* q9 = qw + (size_t)gid * 9;
#pragma unroll
  for (int tp = 0; tp < 9; tp++) Wq[tp * 65536 + gid] = f2h(q9[tp]);
  Wk[gid] = f2h(kw[gid]);
  Wv[gid] = f2h(vw[gid]);
}

// ---------- 1x1 convs: K[bh][m][d], V[bh][d][m] ----------
__global__ __launch_bounds__(256, 2) void k_conv_kv(
    const char* __restrict__ xpad, const unsigned short* __restrict__ Wk,
    const unsigned short* __restrict__ Wv, const float* __restrict__ kb,
    const float* __restrict__ vb, unsigned short* __restrict__ K, unsigned short* __restrict__ V) {
  __shared__ char sm[32768];
  char* Xs = sm;
  char* Ws = sm + 16384;
  int t = threadIdx.x, lane = t & 63, wid = t >> 6, q4 = lane >> 4, l15 = lane & 15;
  int px0 = blockIdx.x * 128;
  int b = px0 >> 12, nn = px0 & 4095;
  int h = blockIdx.y;          // co half / head
  int mode = blockIdx.z;       // 0: K (D[px][co]),  1: V (D[co][px])
  int co0 = h * 128;
  const char* Wsrc = (const char*)(mode ? Wv : Wk);
  int wm = wid & 1, wn = wid >> 1;
  f32x4 acc[4][4] = {};
  for (int c = 0; c < 4; c++) {
    __syncthreads();
    for (int ch = wid * 1024; ch < 16384; ch += 4096) {   // X tile [128px][64ci]
      int o = ch + lane * 16;
      int r = o >> 7;
      int n = nn + r, hh = n >> 6, ww2 = n & 63;
      int col = (o & 127) ^ ((r & 7) << 4);
      gld_lds16(Xs + ch, xpad + ((size_t)((b * 74 + hh + 5) * 74) + ww2 + 5) * 512 + c * 128 + col);
    }
    for (int ch = wid * 1024; ch < 16384; ch += 4096) {   // W tile [128co][64ci]
      int o = ch + lane * 16;
      int r = o >> 7;
      int col = (o & 127) ^ ((r & 7) << 4);
      gld_lds16(Ws + ch, Wsrc + (co0 + r) * 512 + c * 128 + col);
    }
    asm volatile("s_waitcnt vmcnt(0)" ::: "memory");
    __syncthreads();
    int xg = mode ? wn : wm;   // X-frag 64-row group
    int wg = mode ? wm : wn;   // W-frag 64-row group
#pragma unroll
    for (int kt = 0; kt < 2; kt++) {
      f16x8 xf[4], wf[4];
#pragma unroll
      for (int i = 0; i < 4; i++) {
        int rx = xg * 64 + i * 16 + l15;
        xf[i] = *(const f16x8*)(Xs + ((rx * 128 + kt * 64 + q4 * 16) ^ ((rx & 7) << 4)));
        int rw = wg * 64 + i * 16 + l15;
        wf[i] = *(const f16x8*)(Ws + ((rw * 128 + kt * 64 + q4 * 16) ^ ((rw & 7) << 4)));
      }
#pragma unroll
      for (int m = 0; m < 4; m++)
#pragma unroll
        for (int n = 0; n < 4; n++)
          acc[m][n] = mode ? __builtin_amdgcn_mfma_f32_16x16x32_f16(wf[m], xf[n], acc[m][n], 0, 0, 0)
                           : __builtin_amdgcn_mfma_f32_16x16x32_f16(xf[m], wf[n], acc[m][n], 0, 0, 0);
    }
  }
  int bh = b * 2 + h;
  if (mode == 0) {
#pragma unroll
    for (int m = 0; m < 4; m++)
#pragma unroll
      for (int n = 0; n < 4; n++) {
        int dd = wn * 64 + n * 16 + l15;
        float bias = kb[co0 + dd];
#pragma unroll
        for (int j = 0; j < 4; j++) {
          int npix = nn + wm * 64 + m * 16 + q4 * 4 + j;
          K[(size_t)(bh * 4096 + npix) * 128 + dd] = f2h(acc[m][n][j] + bias);
        }
      }
  } else {
#pragma unroll
    for (int m = 0; m < 4; m++)
#pragma unroll
      for (int j = 0; j < 4; j++) {
        int cr = wm * 64 + m * 16 + q4 * 4 + j;
        float bias = vb[co0 + cr];
#pragma unroll
        for (int n = 0; n < 4; n++) {
          int pc = nn + wn * 64 + n * 16 + l15;
          V[(size_t)(bh * 128 + cr) * 4096 + pc] = f2h(acc[m][n][j] + bias);
        }
      }
  }
}

// ---------- dilated 3x3 conv sum(SiLU) -> Q[bh][n][d] ----------
__global__ __launch_bounds__(256, 2) void k_conv_q(
    const char* __restrict__ xpad, const unsigned short* __restrict__ Wq,
    const float* __restrict__ qb, unsigned short* __restrict__ Q) {
  extern __shared__ char sm[];
  char* Bs = sm;               // [3 kw][128 co][64 ci] f16 = 49152
  char* As = sm + 49152;       // 3 x [74 w][64 ci] f16 (pitch 10240)
  int t = threadIdx.x, lane = t & 63, wid = t >> 6, q4 = lane >> 4, l15 = lane & 15;
  int h = blockIdx.x, b = blockIdx.y, ch2 = blockIdx.z;
  int co0 = ch2 * 128;
  int wm = wid & 1, wn = wid >> 1;
  const int dil[3] = {1, 3, 5};
  f32x4 accd[3][2][4] = {};
  for (int kh = 0; kh < 3; kh++) {
    for (int c = 0; c < 4; c++) {
      __syncthreads();
      const char* wq_base = (const char*)Wq + kh * 3 * 131072 + co0 * 512 + c * 128;
      for (int ch = wid * 1024; ch < 49152; ch += 4096) {
        int o = ch + lane * 16;
        int kw = o >> 14;
        int r = (o >> 7) & 127;
        int col = (o & 127) ^ ((r & 7) << 4);
        gld_lds16(Bs + ch, wq_base + kw * 131072 + r * 512 + col);
      }
#pragma unroll
      for (int di = 0; di < 3; di++) {
        int pr = h + (kh - 1) * dil[di] + 5;             // always in [0,74)
        const char* g = xpad + (size_t)((b * 74 + pr) * 74) * 512 + c * 128;
        char* Ad = As + di * 10240;
        for (int ch = wid * 1024; ch < 9472; ch += 4096) {
          int o = ch + lane * 16;
          if (o < 9472) {
            int r = o >> 7;
            int col = (o & 127) ^ ((r & 7) << 4);
            gld_lds16(Ad + ch, g + r * 512 + col);
          }
        }
      }
      asm volatile("s_waitcnt vmcnt(0)" ::: "memory");
      __syncthreads();
#pragma unroll
      for (int di = 0; di < 3; di++) {
        int d = dil[di];
        const char* Ad = As + di * 10240;
#pragma unroll
        for (int kw = 0; kw < 3; kw++) {
          int dw = (kw - 1) * d + 5;
          f16x8 af[2][2], bf[4][2];
#pragma unroll
          for (int m = 0; m < 2; m++)
#pragma unroll
            for (int kt = 0; kt < 2; kt++) {
              int wp = wm * 32 + m * 16 + l15 + dw;      // [0,73]
              af[m][kt] = *(const f16x8*)(Ad + ((wp * 128 + kt * 64 + q4 * 16) ^ ((wp & 7) << 4)));
            }
#pragma unroll
          for (int n = 0; n < 4; n++)
#pragma unroll
            for (int kt = 0; kt < 2; kt++) {
              int rc = wn * 64 + n * 16 + l15;
              bf[n][kt] = *(const f16x8*)(Bs + kw * 16384 + ((rc * 128 + kt * 64 + q4 * 16) ^ ((rc & 7) << 4)));
            }
#pragma unroll
          for (int m = 0; m < 2; m++)
#pragma unroll
            for (int n = 0; n < 4; n++)
#pragma unroll
              for (int kt = 0; kt < 2; kt++)
                accd[di][m][n] = __builtin_amdgcn_mfma_f32_16x16x32_f16(af[m][kt], bf[n][kt], accd[di][m][n], 0, 0, 0);
        }
      }
    }
  }
  const float LOG2E = 1.4426950408889634f;
  const float QSCALE = 0.12751879523176862f;  // log2e / sqrt(128)
#pragma unroll
  for (int n = 0; n < 4; n++) {
    float bias = qb[co0 + wn * 64 + n * 16 + l15];
#pragma unroll
    for (int m = 0; m < 2; m++)
#pragma unroll
      for (int j = 0; j < 4; j++) {
        float s = 0.f;
#pragma unroll
        for (int di = 0; di < 3; di++) {
          float v = accd[di][m][n][j] + bias;
          s += v * v_rcp(1.0f + v_exp2(-v * LOG2E));     // SiLU
        }
        int px = wm * 32 + m * 16 + q4 * 4 + j;
        int dd = wn * 64 + n * 16 + l15;
        int npix = h * 64 + px;
        Q[((size_t)(b * 2 + ch2) * 4096 + npix) * 128 + dd] = f2h(s * QSCALE);
      }
  }
}

// ---------- flash attention: 256 blocks, 4 waves x 32 q-rows, KVBLK=64 ----------
__global__ __launch_bounds__(256) void k_attn(
    const unsigned short* __restrict__ Q, const unsigned short* __restrict__ K,
    const unsigned short* __restrict__ V, float* __restrict__ out) {
  extern __shared__ char sm[];
  char* Qs = sm;                         // [128n][128d] 32KB, swz16
  char* K0 = sm + 32768;                 // [64m][128d] 16KB each, swz16
  char* K1 = sm + 49152;
  char* V0 = sm + 65536;                 // [128d][64m] 16KB each, swz8
  char* V1 = sm + 81920;
  int t = threadIdx.x, lane = t & 63, wid = t >> 6, q4 = lane >> 4, l15 = lane & 15;
  char* Ps = sm + 98304 + wid * 4096;    // per-wave [32n][64m] f16, swz8
  int nb = blockIdx.x, bh = blockIdx.y;
  int b = bh >> 1, hh = bh & 1;
  int n0 = nb * 128;
  const char* Qg = (const char*)(Q + ((size_t)bh * 4096 + n0) * 128);
  const char* Kg = (const char*)(K + (size_t)bh * 4096 * 128);
  const char* Vg = (const char*)(V + (size_t)bh * 128 * 4096);
  // stage Q + first K/V
  for (int ch = wid * 1024; ch < 32768; ch += 4096) {
    int o = ch + lane * 16;
    gld_lds16(Qs + ch, Qg + (o ^ (((o >> 8) & 15) << 4)));
  }
  for (int ch = wid * 1024; ch < 16384; ch += 4096) {
    int o = ch + lane * 16;
    gld_lds16(K0 + ch, Kg + (o ^ (((o >> 8) & 15) << 4)));
  }
  for (int ch = wid * 1024; ch < 16384; ch += 4096) {
    int o = ch + lane * 16;
    int dd = o >> 7;
    int col = (o & 127) ^ ((dd & 7) << 4);
    gld_lds16(V0 + ch, Vg + dd * 8192 + col);
  }
  asm volatile("s_waitcnt vmcnt(0)" ::: "memory");
  __syncthreads();
  // hoist Q fragments (reused for all 64 KV tiles)
  f16x8 qf[2][4];
#pragma unroll
  for (int nt = 0; nt < 2; nt++)
#pragma unroll
    for (int kt = 0; kt < 4; kt++) {
      int rn = wid * 32 + nt * 16 + l15;
      qf[nt][kt] = *(const f16x8*)(Qs + ((rn * 256 + kt * 64 + q4 * 16) ^ ((rn & 15) << 4)));
    }
  f32x4 Ofr[8][2] = {};                  // O^T frags: [d-tile][n-tile], col n = l15
  float mrun[2] = {-3e38f, -3e38f};
  float lrun[2] = {0.f, 0.f};
  for (int it = 0; it < 64; it++) {
    char* Kc = (it & 1) ? K1 : K0;
    char* Vc = (it & 1) ? V1 : V0;
    if (it < 63) {                       // prefetch next tile into other buffer
      char* Kn = (it & 1) ? K0 : K1;
      char* Vn = (it & 1) ? V0 : V1;
      const char* kg = Kg + (size_t)(it + 1) * 16384;
      for (int ch = wid * 1024; ch < 16384; ch += 4096) {
        int o = ch + lane * 16;
        gld_lds16(Kn + ch, kg + (o ^ (((o >> 8) & 15) << 4)));
      }
      const char* vg = Vg + (it + 1) * 128;
      for (int ch = wid * 1024; ch < 16384; ch += 4096) {
        int o = ch + lane * 16;
        int dd = o >> 7;
        int col = (o & 127) ^ ((dd & 7) << 4);
        gld_lds16(Vn + ch, vg + dd * 8192 + col);
      }
    }
    // S^T[m][n] = sum_d K[m][d] Q[n][d]   (swapped operands: softmax state is per-column n = l15)
    f32x4 sT[4][2] = {};
#pragma unroll
    for (int kt = 0; kt < 4; kt++) {
      f16x8 kf[4];
#pragma unroll
      for (int mt = 0; mt < 4; mt++) {
        int rm = mt * 16 + l15;
        kf[mt] = *(const f16x8*)(Kc + ((rm * 256 + kt * 64 + q4 * 16) ^ ((rm & 15) << 4)));
      }
#pragma unroll
      for (int mt = 0; mt < 4; mt++)
#pragma unroll
        for (int nt = 0; nt < 2; nt++)
          sT[mt][nt] = __builtin_amdgcn_mfma_f32_16x16x32_f16(kf[mt], qf[nt][kt], sT[mt][nt], 0, 0, 0);
    }
    // online softmax over m (rows): in-lane 16 + xor16 + xor32
#pragma unroll
    for (int nt = 0; nt < 2; nt++) {
      float mx = sT[0][nt][0];
#pragma unroll
      for (int mt = 0; mt < 4; mt++)
#pragma unroll
        for (int j = 0; j < 4; j++) mx = fmaxf(mx, sT[mt][nt][j]);
      mx = fmaxf(mx, __shfl_xor(mx, 16));
      mx = fmaxf(mx, __shfl_xor(mx, 32));
      float mn = fmaxf(mrun[nt], mx);
      float al = v_exp2(mrun[nt] - mn);
      mrun[nt] = mn;
      float rs = 0.f;
      int rn = nt * 16 + l15;
#pragma unroll
      for (int mt = 0; mt < 4; mt++) {
        float p0 = v_exp2(sT[mt][nt][0] - mn);
        float p1 = v_exp2(sT[mt][nt][1] - mn);
        float p2 = v_exp2(sT[mt][nt][2] - mn);
        float p3 = v_exp2(sT[mt][nt][3] - mn);
        rs += (p0 + p1) + (p2 + p3);
        unsigned u0 = (unsigned)f2h(p0) | ((unsigned)f2h(p1) << 16);
        unsigned u1 = (unsigned)f2h(p2) | ((unsigned)f2h(p3) << 16);
        int byteoff = (rn * 128 + mt * 32 + q4 * 8) ^ ((rn & 7) << 4);
        *(unsigned*)(Ps + byteoff) = u0;
        *(unsigned*)(Ps + byteoff + 4) = u1;
      }
      rs += __shfl_xor(rs, 16);
      rs += __shfl_xor(rs, 32);
      lrun[nt] = lrun[nt] * al + rs;
#pragma unroll
      for (int dt = 0; dt < 8; dt++) Ofr[dt][nt] *= al;
    }
    // O^T += V * P   (A=V rows d, B=P cols n)
#pragma unroll
    for (int kt = 0; kt < 2; kt++) {
      f16x8 pf[2], vf[8];
#pragma unroll
      for (int nt = 0; nt < 2; nt++) {
        int rn = nt * 16 + l15;
        pf[nt] = *(const f16x8*)(Ps + ((rn * 128 + kt * 64 + q4 * 16) ^ ((rn & 7) << 4)));
      }
#pragma unroll
      for (int dt = 0; dt < 8; dt++) {
        int rd = dt * 16 + l15;
        vf[dt] = *(const f16x8*)(Vc + ((rd * 128 + kt * 64 + q4 * 16) ^ ((rd & 7) << 4)));
      }
#pragma unroll
      for (int dt = 0; dt < 8; dt++)
#pragma unroll
        for (int nt = 0; nt < 2; nt++)
          Ofr[dt][nt] = __builtin_amdgcn_mfma_f32_16x16x32_f16(vf[dt], pf[nt], Ofr[dt][nt], 0, 0, 0);
    }
    __syncthreads();
  }
  float li[2] = {v_rcp(lrun[0]), v_rcp(lrun[1])};
  float* og = out + (size_t)(b * 256 + hh * 128) * 4096 + n0 + wid * 32;
#pragma unroll
  for (int dt = 0; dt < 8; dt++)
#pragma unroll
    for (int nt = 0; nt < 2; nt++)
#pragma unroll
      for (int j = 0; j < 4; j++) {
        int dd = dt * 16 + q4 * 4 + j;
        og[(size_t)dd * 4096 + nt * 16 + l15] = Ofr[dt][nt][j] * li[nt];
      }
}

extern "C" void kernel_launch(void* const* d_in, const int* in_sizes, int n_in,
                              void* d_out, int out_size, void* d_ws, size_t ws_size,
                              hipStream_t stream) {
  (void)in_sizes; (void)n_in; (void)out_size;
  const float* x  = (const float*)d_in[0];
  const float* qw = (const float*)d_in[1];
  const float* qb = (const float*)d_in[2];
  const float* kw = (const float*)d_in[3];
  const float* kb = (const float*)d_in[4];
  const float* vw = (const float*)d_in[5];
  const float* vb = (const float*)d_in[6];
  char* ws = (char*)d_ws;
  if (ws_size < 37822464) return;
  char* xpad = ws;
  unsigned short* Wq = (unsigned short*)(ws + 11214848);
  unsigned short* Wk = (unsigned short*)(ws + 12394496);
  unsigned short* Wv = (unsigned short*)(ws + 12525568);
  unsigned short* Qb = (unsigned short*)(ws + 12656640);
  unsigned short* Kb = (unsigned short*)(ws + 21045248);
  unsigned short* Vb = (unsigned short*)(ws + 29433856);
  hipMemsetAsync(xpad, 0, 11214848, stream);
  k_prep_x<<<dim3(64, 4), dim3(256), 0, stream>>>(x, xpad);
  k_prep_w<<<dim3(256), dim3(256), 0, stream>>>(qw, kw, vw, Wq, Wk, Wv);
  k_conv_kv<<<dim3(128, 2, 2), dim3(256), 0, stream>>>(xpad, Wk, Wv, kb, vb, Kb, Vb);
  k_conv_q<<<dim3(64, 4, 2), dim3(256), 79872, stream>>>(xpad, Wq, qb, Qb);
  k_attn<<<dim3(32, 8), dim3(256), 114688, stream>>>(Qb, Kb, Vb, (float*)d_out);
}

// Round 3
// 180.637 us; speedup vs baseline: 1.2556x; 1.2556x over previous
//
#include <hip/hip_runtime.h>
#include <cstdint>

typedef __attribute__((ext_vector_type(8))) _Float16 f16x8;
typedef __attribute__((ext_vector_type(4))) float f32x4;

#define DEV static __device__ __forceinline__

DEV void gld_lds16(void* lds_base, const void* gsrc) {
  __builtin_amdgcn_global_load_lds(
      (const __attribute__((address_space(1))) unsigned int*)gsrc,
      (__attribute__((address_space(3))) unsigned int*)lds_base,
      16, 0, 0);
}
DEV unsigned short f2h(float f) {
  _Float16 h = (_Float16)f;
  return __builtin_bit_cast(unsigned short, h);
}
DEV float h2f(unsigned short u) {
  _Float16 h = __builtin_bit_cast(_Float16, u);
  return (float)h;
}
DEV unsigned pk2h(float a, float b) {
  auto h2 = __builtin_amdgcn_cvt_pkrtz(a, b);
  return __builtin_bit_cast(unsigned, h2);
}
DEV float v_exp2(float x) { float r; asm("v_exp_f32 %0, %1" : "=v"(r) : "v"(x)); return r; }
DEV float v_rcp(float x) { float r; asm("v_rcp_f32 %0, %1" : "=v"(r) : "v"(x)); return r; }

// ---------------- geometry ----------------
// B=4, C=256, H=W=64, N=4096, heads=2, hd=128
// ws layout (bytes):
//   Xpad [4][74][74][256] f16 : 0        .. 11214848   (reused as O1 f16 [8][128][4096] during attn)
//   Wq [3][3][256][256] f16   : 11214848 .. 12394496   (reused as ml buf [2][8][4096][2] f32 during attn)
//   Wk [256][256] f16         : 12394496 .. 12525568
//   Wv [256][256] f16         : 12525568 .. 12656640
//   Q  [8][4096][128] f16     : 12656640 .. 21045248   (pre-scaled by log2e/sqrt(128))
//   K  [8][4096][128] f16     : 21045248 .. 29433856
//   V  [8][128][4096] f16     : 29433856 .. 37822464

// ---------- prep: x (f32 NCHW) -> Xpad (f16, pixel-major, halo 5) ----------
__global__ __launch_bounds__(256) void k_prep_x(const float* __restrict__ x, char* __restrict__ xpad) {
  __shared__ float xs[32 * 257];
  int h = blockIdx.x, b = blockIdx.y, t = threadIdx.x;
  const float* xb = x + (size_t)b * 1048576 + h * 64;
  for (int half = 0; half < 2; half++) {
    int w0 = half * 32;
    for (int kk = 0; kk < 32; kk++) {
      int flat = kk * 256 + t;       // ci*32 + w
      int ci = flat >> 5, w = flat & 31;
      xs[w * 257 + ci] = xb[ci * 4096 + w0 + w];
    }
    __syncthreads();
    for (int g = 0; g < 4; g++) {
      int w = g * 8 + (t >> 5);
      int cg = t & 31;               // 8-ci chunk
      float v0 = xs[w * 257 + cg * 8 + 0], v1 = xs[w * 257 + cg * 8 + 1];
      float v2 = xs[w * 257 + cg * 8 + 2], v3 = xs[w * 257 + cg * 8 + 3];
      float v4 = xs[w * 257 + cg * 8 + 4], v5 = xs[w * 257 + cg * 8 + 5];
      float v6 = xs[w * 257 + cg * 8 + 6], v7 = xs[w * 257 + cg * 8 + 7];
      uint4 pk;
      pk.x = pk2h(v0, v1);
      pk.y = pk2h(v2, v3);
      pk.z = pk2h(v4, v5);
      pk.w = pk2h(v6, v7);
      *(uint4*)(xpad + ((size_t)((b * 74 + h + 5) * 74) + w0 + w + 5) * 512 + cg * 16) = pk;
    }
    __syncthreads();
  }
}

// ---------- prep: weights -> f16 ----------
__global__ __launch_bounds__(256) void k_prep_w(
    const float* __restrict__ qw, const float* __restrict__ kw, const float* __restrict__ vw,
    unsigned short* __restrict__ Wq, unsigned short* __restrict__ Wk, unsigned short* __restrict__ Wv) {
  int gid = blockIdx.x * 256 + threadIdx.x;   // co*256+ci
  const float* q9 = qw + (size_t)gid * 9;
#pragma unroll
  for (int tp = 0; tp < 9; tp++) Wq[tp * 65536 + gid] = f2h(q9[tp]);
  Wk[gid] = f2h(kw[gid]);
  Wv[gid] = f2h(vw[gid]);
}

// ---------- 1x1 convs: K[bh][m][d], V[bh][d][m] ----------
__global__ __launch_bounds__(256, 2) void k_conv_kv(
    const char* __restrict__ xpad, const unsigned short* __restrict__ Wk,
    const unsigned short* __restrict__ Wv, const float* __restrict__ kb,
    const float* __restrict__ vb, unsigned short* __restrict__ K, unsigned short* __restrict__ V) {
  __shared__ char sm[32768];
  char* Xs = sm;
  char* Ws = sm + 16384;
  int t = threadIdx.x, lane = t & 63, wid = t >> 6, q4 = lane >> 4, l15 = lane & 15;
  int px0 = blockIdx.x * 128;
  int b = px0 >> 12, nn = px0 & 4095;
  int h = blockIdx.y;          // co half / head
  int mode = blockIdx.z;       // 0: K (D[px][co]),  1: V (D[co][px])
  int co0 = h * 128;
  const char* Wsrc = (const char*)(mode ? Wv : Wk);
  int wm = wid & 1, wn = wid >> 1;
  f32x4 acc[4][4] = {};
  for (int c = 0; c < 4; c++) {
    __syncthreads();
    for (int ch = wid * 1024; ch < 16384; ch += 4096) {   // X tile [128px][64ci]
      int o = ch + lane * 16;
      int r = o >> 7;
      int n = nn + r, hh = n >> 6, ww2 = n & 63;
      int col = (o & 127) ^ ((r & 7) << 4);
      gld_lds16(Xs + ch, xpad + ((size_t)((b * 74 + hh + 5) * 74) + ww2 + 5) * 512 + c * 128 + col);
    }
    for (int ch = wid * 1024; ch < 16384; ch += 4096) {   // W tile [128co][64ci]
      int o = ch + lane * 16;
      int r = o >> 7;
      int col = (o & 127) ^ ((r & 7) << 4);
      gld_lds16(Ws + ch, Wsrc + (co0 + r) * 512 + c * 128 + col);
    }
    asm volatile("s_waitcnt vmcnt(0)" ::: "memory");
    __syncthreads();
    int xg = mode ? wn : wm;   // X-frag 64-row group
    int wg = mode ? wm : wn;   // W-frag 64-row group
#pragma unroll
    for (int kt = 0; kt < 2; kt++) {
      f16x8 xf[4], wf[4];
#pragma unroll
      for (int i = 0; i < 4; i++) {
        int rx = xg * 64 + i * 16 + l15;
        xf[i] = *(const f16x8*)(Xs + ((rx * 128 + kt * 64 + q4 * 16) ^ ((rx & 7) << 4)));
        int rw = wg * 64 + i * 16 + l15;
        wf[i] = *(const f16x8*)(Ws + ((rw * 128 + kt * 64 + q4 * 16) ^ ((rw & 7) << 4)));
      }
#pragma unroll
      for (int m = 0; m < 4; m++)
#pragma unroll
        for (int n = 0; n < 4; n++)
          acc[m][n] = mode ? __builtin_amdgcn_mfma_f32_16x16x32_f16(wf[m], xf[n], acc[m][n], 0, 0, 0)
                           : __builtin_amdgcn_mfma_f32_16x16x32_f16(xf[m], wf[n], acc[m][n], 0, 0, 0);
    }
  }
  int bh = b * 2 + h;
  if (mode == 0) {
#pragma unroll
    for (int m = 0; m < 4; m++)
#pragma unroll
      for (int n = 0; n < 4; n++) {
        int dd = wn * 64 + n * 16 + l15;
        float bias = kb[co0 + dd];
#pragma unroll
        for (int j = 0; j < 4; j++) {
          int npix = nn + wm * 64 + m * 16 + q4 * 4 + j;
          K[(size_t)(bh * 4096 + npix) * 128 + dd] = f2h(acc[m][n][j] + bias);
        }
      }
  } else {
#pragma unroll
    for (int m = 0; m < 4; m++)
#pragma unroll
      for (int j = 0; j < 4; j++) {
        int cr = wm * 64 + m * 16 + q4 * 4 + j;
        float bias = vb[co0 + cr];
#pragma unroll
        for (int n = 0; n < 4; n++) {
          int pc = nn + wn * 64 + n * 16 + l15;
          V[(size_t)(bh * 128 + cr) * 4096 + pc] = f2h(acc[m][n][j] + bias);
        }
      }
  }
}

// ---------- dilated 3x3 conv sum(SiLU) -> Q[bh][n][d] ----------
__global__ __launch_bounds__(256, 2) void k_conv_q(
    const char* __restrict__ xpad, const unsigned short* __restrict__ Wq,
    const float* __restrict__ qb, unsigned short* __restrict__ Q) {
  extern __shared__ char sm[];
  char* Bs = sm;               // [3 kw][128 co][64 ci] f16 = 49152
  char* As = sm + 49152;       // 3 x [74 w][64 ci] f16 (pitch 10240)
  int t = threadIdx.x, lane = t & 63, wid = t >> 6, q4 = lane >> 4, l15 = lane & 15;
  int h = blockIdx.x, b = blockIdx.y, ch2 = blockIdx.z;
  int co0 = ch2 * 128;
  int wm = wid & 1, wn = wid >> 1;
  const int dil[3] = {1, 3, 5};
  f32x4 accd[3][2][4] = {};
  for (int kh = 0; kh < 3; kh++) {
    for (int c = 0; c < 4; c++) {
      __syncthreads();
      const char* wq_base = (const char*)Wq + kh * 3 * 131072 + co0 * 512 + c * 128;
      for (int ch = wid * 1024; ch < 49152; ch += 4096) {
        int o = ch + lane * 16;
        int kw = o >> 14;
        int r = (o >> 7) & 127;
        int col = (o & 127) ^ ((r & 7) << 4);
        gld_lds16(Bs + ch, wq_base + kw * 131072 + r * 512 + col);
      }
#pragma unroll
      for (int di = 0; di < 3; di++) {
        int pr = h + (kh - 1) * dil[di] + 5;             // always in [0,74)
        const char* g = xpad + (size_t)((b * 74 + pr) * 74) * 512 + c * 128;
        char* Ad = As + di * 10240;
        for (int ch = wid * 1024; ch < 9472; ch += 4096) {
          int o = ch + lane * 16;
          if (o < 9472) {
            int r = o >> 7;
            int col = (o & 127) ^ ((r & 7) << 4);
            gld_lds16(Ad + ch, g + r * 512 + col);
          }
        }
      }
      asm volatile("s_waitcnt vmcnt(0)" ::: "memory");
      __syncthreads();
#pragma unroll
      for (int di = 0; di < 3; di++) {
        int d = dil[di];
        const char* Ad = As + di * 10240;
#pragma unroll
        for (int kw = 0; kw < 3; kw++) {
          int dw = (kw - 1) * d + 5;
          f16x8 af[2][2], bf[4][2];
#pragma unroll
          for (int m = 0; m < 2; m++)
#pragma unroll
            for (int kt = 0; kt < 2; kt++) {
              int wp = wm * 32 + m * 16 + l15 + dw;      // [0,73]
              af[m][kt] = *(const f16x8*)(Ad + ((wp * 128 + kt * 64 + q4 * 16) ^ ((wp & 7) << 4)));
            }
#pragma unroll
          for (int n = 0; n < 4; n++)
#pragma unroll
            for (int kt = 0; kt < 2; kt++) {
              int rc = wn * 64 + n * 16 + l15;
              bf[n][kt] = *(const f16x8*)(Bs + kw * 16384 + ((rc * 128 + kt * 64 + q4 * 16) ^ ((rc & 7) << 4)));
            }
#pragma unroll
          for (int m = 0; m < 2; m++)
#pragma unroll
            for (int n = 0; n < 4; n++)
#pragma unroll
              for (int kt = 0; kt < 2; kt++)
                accd[di][m][n] = __builtin_amdgcn_mfma_f32_16x16x32_f16(af[m][kt], bf[n][kt], accd[di][m][n], 0, 0, 0);
        }
      }
    }
  }
  const float LOG2E = 1.4426950408889634f;
  const float QSCALE = 0.12751879523176862f;  // log2e / sqrt(128)
#pragma unroll
  for (int n = 0; n < 4; n++) {
    float bias = qb[co0 + wn * 64 + n * 16 + l15];
#pragma unroll
    for (int m = 0; m < 2; m++)
#pragma unroll
      for (int j = 0; j < 4; j++) {
        float s = 0.f;
#pragma unroll
        for (int di = 0; di < 3; di++) {
          float v = accd[di][m][n][j] + bias;
          s += v * v_rcp(1.0f + v_exp2(-v * LOG2E));     // SiLU
        }
        int px = wm * 32 + m * 16 + q4 * 4 + j;
        int dd = wn * 64 + n * 16 + l15;
        int npix = h * 64 + px;
        Q[((size_t)(b * 2 + ch2) * 4096 + npix) * 128 + dd] = f2h(s * QSCALE);
      }
  }
}

// ---------- flash attention, KV-split in 2 halves: grid (32, 8, 2), 2 blocks/CU ----------
// half 0: writes unnormalized O (f32) to out + (m,l) to mlbuf
// half 1: writes normalized O (f16) to o1buf + (m,l) to mlbuf
__global__ __launch_bounds__(256, 2) void k_attn(
    const unsigned short* __restrict__ Q, const unsigned short* __restrict__ K,
    const unsigned short* __restrict__ V, float* __restrict__ out,
    unsigned short* __restrict__ o1buf, float* __restrict__ mlbuf) {
  extern __shared__ char sm[];
  char* K0 = sm;                         // [64m][128d] 16KB each, swz16
  char* K1 = sm + 16384;
  char* V0 = sm + 32768;                 // [128d][64m] 16KB each, swz8
  char* V1 = sm + 49152;
  int t = threadIdx.x, lane = t & 63, wid = t >> 6, q4 = lane >> 4, l15 = lane & 15;
  char* Ps = sm + 65536 + wid * 4096;    // per-wave [32n][64m] f16, swz8
  int nb = blockIdx.x, bh = blockIdx.y, half = blockIdx.z;
  int b = bh >> 1, hh = bh & 1;
  int n0 = nb * 128;
  const char* Qg = (const char*)(Q + ((size_t)bh * 4096 + n0) * 128);
  const char* Kg = (const char*)(K + (size_t)bh * 4096 * 128) + half * 524288;   // 32 tiles * 16KB
  const char* Vg = (const char*)(V + (size_t)bh * 128 * 4096) + half * 4096;     // 2048 m * 2B
  // Q fragments direct from global (read once; no LDS staging)
  f16x8 qf[2][4];
#pragma unroll
  for (int nt = 0; nt < 2; nt++)
#pragma unroll
    for (int kt = 0; kt < 4; kt++) {
      int rn = wid * 32 + nt * 16 + l15;
      qf[nt][kt] = *(const f16x8*)(Qg + (size_t)rn * 256 + kt * 64 + q4 * 16);
    }
  // stage first K/V tile of this half
  for (int ch = wid * 1024; ch < 16384; ch += 4096) {
    int o = ch + lane * 16;
    gld_lds16(K0 + ch, Kg + (o ^ (((o >> 8) & 15) << 4)));
  }
  for (int ch = wid * 1024; ch < 16384; ch += 4096) {
    int o = ch + lane * 16;
    int dd = o >> 7;
    int col = (o & 127) ^ ((dd & 7) << 4);
    gld_lds16(V0 + ch, Vg + dd * 8192 + col);
  }
  asm volatile("s_waitcnt vmcnt(0)" ::: "memory");
  __syncthreads();
  f32x4 Ofr[8][2] = {};                  // O^T frags: [d-tile][n-tile], col n = l15
  float mrun[2] = {-3e38f, -3e38f};
  float lrun[2] = {0.f, 0.f};
  for (int it = 0; it < 32; it++) {
    char* Kc = (it & 1) ? K1 : K0;
    char* Vc = (it & 1) ? V1 : V0;
    if (it < 31) {                       // prefetch next tile into other buffer
      char* Kn = (it & 1) ? K0 : K1;
      char* Vn = (it & 1) ? V0 : V1;
      const char* kg = Kg + (size_t)(it + 1) * 16384;
      for (int ch = wid * 1024; ch < 16384; ch += 4096) {
        int o = ch + lane * 16;
        gld_lds16(Kn + ch, kg + (o ^ (((o >> 8) & 15) << 4)));
      }
      const char* vg = Vg + (it + 1) * 128;
      for (int ch = wid * 1024; ch < 16384; ch += 4096) {
        int o = ch + lane * 16;
        int dd = o >> 7;
        int col = (o & 127) ^ ((dd & 7) << 4);
        gld_lds16(Vn + ch, vg + dd * 8192 + col);
      }
    }
    // S^T[m][n] = sum_d K[m][d] Q[n][d]   (swapped operands: softmax state is per-column n = l15)
    f32x4 sT[4][2] = {};
#pragma unroll
    for (int kt = 0; kt < 4; kt++) {
      f16x8 kf[4];
#pragma unroll
      for (int mt = 0; mt < 4; mt++) {
        int rm = mt * 16 + l15;
        kf[mt] = *(const f16x8*)(Kc + ((rm * 256 + kt * 64 + q4 * 16) ^ ((rm & 15) << 4)));
      }
#pragma unroll
      for (int mt = 0; mt < 4; mt++)
#pragma unroll
        for (int nt = 0; nt < 2; nt++)
          sT[mt][nt] = __builtin_amdgcn_mfma_f32_16x16x32_f16(kf[mt], qf[nt][kt], sT[mt][nt], 0, 0, 0);
    }
    // online softmax over m (rows), defer-max rescale (threshold 8)
#pragma unroll
    for (int nt = 0; nt < 2; nt++) {
      float mx = sT[0][nt][0];
#pragma unroll
      for (int mt = 0; mt < 4; mt++)
#pragma unroll
        for (int j = 0; j < 4; j++) mx = fmaxf(mx, sT[mt][nt][j]);
      mx = fmaxf(mx, __shfl_xor(mx, 16));
      mx = fmaxf(mx, __shfl_xor(mx, 32));
      float mn = mrun[nt];
      if (!__all(mx - mn <= 8.f)) {      // rare: real max growth -> rescale
        mn = fmaxf(mrun[nt], mx);
        float al = v_exp2(mrun[nt] - mn);
        mrun[nt] = mn;
        lrun[nt] *= al;
#pragma unroll
        for (int dt = 0; dt < 8; dt++) Ofr[dt][nt] *= al;
      }
      float rs = 0.f;
      int rn = nt * 16 + l15;
#pragma unroll
      for (int mt = 0; mt < 4; mt++) {
        float p0 = v_exp2(sT[mt][nt][0] - mn);
        float p1 = v_exp2(sT[mt][nt][1] - mn);
        float p2 = v_exp2(sT[mt][nt][2] - mn);
        float p3 = v_exp2(sT[mt][nt][3] - mn);
        rs += (p0 + p1) + (p2 + p3);
        uint2 u;
        u.x = pk2h(p0, p1);
        u.y = pk2h(p2, p3);
        int byteoff = (rn * 128 + mt * 32 + q4 * 8) ^ ((rn & 7) << 4);
        *(uint2*)(Ps + byteoff) = u;
      }
      rs += __shfl_xor(rs, 16);
      rs += __shfl_xor(rs, 32);
      lrun[nt] += rs;
    }
    // O^T += V * P   (A=V rows d, B=P cols n)
#pragma unroll
    for (int kt = 0; kt < 2; kt++) {
      f16x8 pf[2], vf[8];
#pragma unroll
      for (int nt = 0; nt < 2; nt++) {
        int rn = nt * 16 + l15;
        pf[nt] = *(const f16x8*)(Ps + ((rn * 128 + kt * 64 + q4 * 16) ^ ((rn & 7) << 4)));
      }
#pragma unroll
      for (int dt = 0; dt < 8; dt++) {
        int rd = dt * 16 + l15;
        vf[dt] = *(const f16x8*)(Vc + ((rd * 128 + kt * 64 + q4 * 16) ^ ((rd & 7) << 4)));
      }
#pragma unroll
      for (int dt = 0; dt < 8; dt++)
#pragma unroll
        for (int nt = 0; nt < 2; nt++)
          Ofr[dt][nt] = __builtin_amdgcn_mfma_f32_16x16x32_f16(vf[dt], pf[nt], Ofr[dt][nt], 0, 0, 0);
    }
    __syncthreads();
  }
  // write (m,l) per q-column
  if (q4 == 0) {
#pragma unroll
    for (int nt = 0; nt < 2; nt++) {
      int n = n0 + wid * 32 + nt * 16 + l15;
      float2 ml;
      ml.x = mrun[nt];
      ml.y = lrun[nt];
      *(float2*)(mlbuf + ((size_t)(half * 8 + bh) * 4096 + n) * 2) = ml;
    }
  }
  if (half == 0) {
    float* og = out + (size_t)(b * 256 + hh * 128) * 4096 + n0 + wid * 32;
#pragma unroll
    for (int dt = 0; dt < 8; dt++)
#pragma unroll
      for (int nt = 0; nt < 2; nt++)
#pragma unroll
        for (int j = 0; j < 4; j++) {
          int dd = dt * 16 + q4 * 4 + j;
          og[(size_t)dd * 4096 + nt * 16 + l15] = Ofr[dt][nt][j];
        }
  } else {
    float li[2] = {v_rcp(lrun[0]), v_rcp(lrun[1])};
    unsigned short* og = o1buf + (size_t)bh * 128 * 4096 + n0 + wid * 32;
#pragma unroll
    for (int dt = 0; dt < 8; dt++)
#pragma unroll
      for (int nt = 0; nt < 2; nt++)
#pragma unroll
        for (int j = 0; j < 4; j++) {
          int dd = dt * 16 + q4 * 4 + j;
          og[(size_t)dd * 4096 + nt * 16 + l15] = f2h(Ofr[dt][nt][j] * li[nt]);
        }
  }
}

// ---------- combine the two KV halves (in-place on out) ----------
__global__ __launch_bounds__(256) void k_combine(
    float* __restrict__ out, const unsigned short* __restrict__ o1,
    const float* __restrict__ ml) {
  int tid = blockIdx.x * 256 + threadIdx.x;    // bits: [0:11]=n, [12:14]=dg, [15:17]=bh
  int n = tid & 4095, dg = (tid >> 12) & 7, bh = tid >> 15;
  float2 ml0 = *(const float2*)(ml + ((size_t)bh * 4096 + n) * 2);
  float2 ml1 = *(const float2*)(ml + ((size_t)(8 + bh) * 4096 + n) * 2);
  float ms = fmaxf(ml0.x, ml1.x);
  float a0 = v_exp2(ml0.x - ms);
  float w1 = ml1.y * v_exp2(ml1.x - ms);
  float inv = 1.f / (ml0.y * a0 + w1);
  size_t ob = ((size_t)((bh >> 1) * 256 + (bh & 1) * 128 + dg * 16)) * 4096 + n;
  size_t o1b = ((size_t)(bh * 128 + dg * 16)) * 4096 + n;
#pragma unroll 4
  for (int j = 0; j < 16; j++) {
    float v0 = out[ob + (size_t)j * 4096];
    float v1 = h2f(o1[o1b + (size_t)j * 4096]);
    out[ob + (size_t)j * 4096] = (v0 * a0 + v1 * w1) * inv;
  }
}

extern "C" void kernel_launch(void* const* d_in, const int* in_sizes, int n_in,
                              void* d_out, int out_size, void* d_ws, size_t ws_size,
                              hipStream_t stream) {
  (void)in_sizes; (void)n_in; (void)out_size;
  const float* x  = (const float*)d_in[0];
  const float* qw = (const float*)d_in[1];
  const float* qb = (const float*)d_in[2];
  const float* kw = (const float*)d_in[3];
  const float* kb = (const float*)d_in[4];
  const float* vw = (const float*)d_in[5];
  const float* vb = (const float*)d_in[6];
  char* ws = (char*)d_ws;
  if (ws_size < 37822464) return;
  char* xpad = ws;
  unsigned short* Wq = (unsigned short*)(ws + 11214848);
  unsigned short* Wk = (unsigned short*)(ws + 12394496);
  unsigned short* Wv = (unsigned short*)(ws + 12525568);
  unsigned short* Qb = (unsigned short*)(ws + 12656640);
  unsigned short* Kb = (unsigned short*)(ws + 21045248);
  unsigned short* Vb = (unsigned short*)(ws + 29433856);
  unsigned short* O1 = (unsigned short*)ws;            // reuse xpad after convs (8.4MB)
  float* ML = (float*)(ws + 11214848);                 // reuse Wq after convs (512KB)
  hipMemsetAsync(xpad, 0, 11214848, stream);
  k_prep_x<<<dim3(64, 4), dim3(256), 0, stream>>>(x, xpad);
  k_prep_w<<<dim3(256), dim3(256), 0, stream>>>(qw, kw, vw, Wq, Wk, Wv);
  k_conv_kv<<<dim3(128, 2, 2), dim3(256), 0, stream>>>(xpad, Wk, Wv, kb, vb, Kb, Vb);
  k_conv_q<<<dim3(64, 4, 2), dim3(256), 79872, stream>>>(xpad, Wq, qb, Qb);
  k_attn<<<dim3(32, 8, 2), dim3(256), 81920, stream>>>(Qb, Kb, Vb, (float*)d_out, O1, ML);
  k_combine<<<dim3(1024), dim3(256), 0, stream>>>((float*)d_out, O1, ML);
}

// Round 5
// 176.694 us; speedup vs baseline: 1.2836x; 1.0223x over previous
//
#include <hip/hip_runtime.h>
#include <cstdint>

typedef __attribute__((ext_vector_type(8))) _Float16 f16x8;
typedef __attribute__((ext_vector_type(4))) float f32x4;

#define DEV static __device__ __forceinline__

DEV void gld_lds16(void* lds_base, const void* gsrc) {
  __builtin_amdgcn_global_load_lds(
      (const __attribute__((address_space(1))) unsigned int*)gsrc,
      (__attribute__((address_space(3))) unsigned int*)lds_base,
      16, 0, 0);
}
DEV unsigned short f2h(float f) {
  _Float16 h = (_Float16)f;
  return __builtin_bit_cast(unsigned short, h);
}
DEV float h2f(unsigned short u) {
  _Float16 h = __builtin_bit_cast(_Float16, u);
  return (float)h;
}
DEV unsigned pk2h(float a, float b) {
  auto h2 = __builtin_amdgcn_cvt_pkrtz(a, b);
  return __builtin_bit_cast(unsigned, h2);
}
DEV float v_exp2(float x) { float r; asm("v_exp_f32 %0, %1" : "=v"(r) : "v"(x)); return r; }
DEV float v_rcp(float x) { float r; asm("v_rcp_f32 %0, %1" : "=v"(r) : "v"(x)); return r; }

// ---------------- geometry ----------------
// B=4, C=256, H=W=64, N=4096, heads=2, hd=128
// ws layout (bytes):
//   Xpad [4][74][74][256] f16 : 0        .. 11214848   (reused as O1 f16 [8][128][4096] during attn)
//   Wq [3][3][256][256] f16   : 11214848 .. 12394496   (reused as ml buf [2][8][4096][2] f32 during attn)
//   Wk [256][256] f16         : 12394496 .. 12525568
//   Wv [256][256] f16         : 12525568 .. 12656640
//   Q  [8][4096][128] f16     : 12656640 .. 21045248   (pre-scaled by log2e/sqrt(128))
//   K  [8][4096][128] f16     : 21045248 .. 29433856
//   V  [8][128][4096] f16     : 29433856 .. 37822464   (m-permuted per 64-block: s=[m5,m3,m2,m4,m1,m0])

// ---------- prep: x (f32 NCHW) -> Xpad (f16, pixel-major, halo 5) ----------
__global__ __launch_bounds__(256) void k_prep_x(const float* __restrict__ x, char* __restrict__ xpad) {
  __shared__ float xs[32 * 257];
  int h = blockIdx.x, b = blockIdx.y, t = threadIdx.x;
  const float* xb = x + (size_t)b * 1048576 + h * 64;
  for (int half = 0; half < 2; half++) {
    int w0 = half * 32;
    for (int kk = 0; kk < 32; kk++) {
      int flat = kk * 256 + t;       // ci*32 + w
      int ci = flat >> 5, w = flat & 31;
      xs[w * 257 + ci] = xb[ci * 4096 + w0 + w];
    }
    __syncthreads();
    for (int g = 0; g < 4; g++) {
      int w = g * 8 + (t >> 5);
      int cg = t & 31;               // 8-ci chunk
      float v0 = xs[w * 257 + cg * 8 + 0], v1 = xs[w * 257 + cg * 8 + 1];
      float v2 = xs[w * 257 + cg * 8 + 2], v3 = xs[w * 257 + cg * 8 + 3];
      float v4 = xs[w * 257 + cg * 8 + 4], v5 = xs[w * 257 + cg * 8 + 5];
      float v6 = xs[w * 257 + cg * 8 + 6], v7 = xs[w * 257 + cg * 8 + 7];
      uint4 pk;
      pk.x = pk2h(v0, v1);
      pk.y = pk2h(v2, v3);
      pk.z = pk2h(v4, v5);
      pk.w = pk2h(v6, v7);
      *(uint4*)(xpad + ((size_t)((b * 74 + h + 5) * 74) + w0 + w + 5) * 512 + cg * 16) = pk;
    }
    __syncthreads();
  }
}

// ---------- prep: weights -> f16 ----------
__global__ __launch_bounds__(256) void k_prep_w(
    const float* __restrict__ qw, const float* __restrict__ kw, const float* __restrict__ vw,
    unsigned short* __restrict__ Wq, unsigned short* __restrict__ Wk, unsigned short* __restrict__ Wv) {
  int gid = blockIdx.x * 256 + threadIdx.x;   // co*256+ci
  const float* q9 = qw + (size_t)gid * 9;
#pragma unroll
  for (int tp = 0; tp < 9; tp++) Wq[tp * 65536 + gid] = f2h(q9[tp]);
  Wk[gid] = f2h(kw[gid]);
  Wv[gid] = f2h(vw[gid]);
}

// ---------- 1x1 convs: K[bh][m][d], V[bh][d][s(m)] ----------
__global__ __launch_bounds__(256, 2) void k_conv_kv(
    const char* __restrict__ xpad, const unsigned short* __restrict__ Wk,
    const unsigned short* __restrict__ Wv, const float* __restrict__ kb,
    const float* __restrict__ vb, unsigned short* __restrict__ K, unsigned short* __restrict__ V) {
  __shared__ char sm[32768];
  char* Xs = sm;
  char* Ws = sm + 16384;
  int t = threadIdx.x, lane = t & 63, wid = t >> 6, q4 = lane >> 4, l15 = lane & 15;
  int px0 = blockIdx.x * 128;
  int b = px0 >> 12, nn = px0 & 4095;
  int h = blockIdx.y;          // co half / head
  int mode = blockIdx.z;       // 0: K (D[px][co]),  1: V (D[co][px])
  int co0 = h * 128;
  const char* Wsrc = (const char*)(mode ? Wv : Wk);
  int wm = wid & 1, wn = wid >> 1;
  f32x4 acc[4][4] = {};
  for (int c = 0; c < 4; c++) {
    __syncthreads();
    for (int ch = wid * 1024; ch < 16384; ch += 4096) {   // X tile [128px][64ci]
      int o = ch + lane * 16;
      int r = o >> 7;
      int n = nn + r, hh = n >> 6, ww2 = n & 63;
      int col = (o & 127) ^ ((r & 7) << 4);
      gld_lds16(Xs + ch, xpad + ((size_t)((b * 74 + hh + 5) * 74) + ww2 + 5) * 512 + c * 128 + col);
    }
    for (int ch = wid * 1024; ch < 16384; ch += 4096) {   // W tile [128co][64ci]
      int o = ch + lane * 16;
      int r = o >> 7;
      int col = (o & 127) ^ ((r & 7) << 4);
      gld_lds16(Ws + ch, Wsrc + (co0 + r) * 512 + c * 128 + col);
    }
    asm volatile("s_waitcnt vmcnt(0)" ::: "memory");
    __syncthreads();
    int xg = mode ? wn : wm;   // X-frag 64-row group
    int wg = mode ? wm : wn;   // W-frag 64-row group
#pragma unroll
    for (int kt = 0; kt < 2; kt++) {
      f16x8 xf[4], wf[4];
#pragma unroll
      for (int i = 0; i < 4; i++) {
        int rx = xg * 64 + i * 16 + l15;
        xf[i] = *(const f16x8*)(Xs + ((rx * 128 + kt * 64 + q4 * 16) ^ ((rx & 7) << 4)));
        int rw = wg * 64 + i * 16 + l15;
        wf[i] = *(const f16x8*)(Ws + ((rw * 128 + kt * 64 + q4 * 16) ^ ((rw & 7) << 4)));
      }
#pragma unroll
      for (int m = 0; m < 4; m++)
#pragma unroll
        for (int n = 0; n < 4; n++)
          acc[m][n] = mode ? __builtin_amdgcn_mfma_f32_16x16x32_f16(wf[m], xf[n], acc[m][n], 0, 0, 0)
                           : __builtin_amdgcn_mfma_f32_16x16x32_f16(xf[m], wf[n], acc[m][n], 0, 0, 0);
    }
  }
  int bh = b * 2 + h;
  if (mode == 0) {
#pragma unroll
    for (int m = 0; m < 4; m++)
#pragma unroll
      for (int n = 0; n < 4; n++) {
        int dd = wn * 64 + n * 16 + l15;
        float bias = kb[co0 + dd];
#pragma unroll
        for (int j = 0; j < 4; j++) {
          int npix = nn + wm * 64 + m * 16 + q4 * 4 + j;
          K[(size_t)(bh * 4096 + npix) * 128 + dd] = f2h(acc[m][n][j] + bias);
        }
      }
  } else {
#pragma unroll
    for (int m = 0; m < 4; m++)
#pragma unroll
      for (int j = 0; j < 4; j++) {
        int cr = wm * 64 + m * 16 + q4 * 4 + j;
        float bias = vb[co0 + cr];
#pragma unroll
        for (int n = 0; n < 4; n++) {
          // m-permuted storage within each 64-block: m_local = n*16 + l15
          // -> s = (n>>1)*32 + (l15>>2)*8 + (n&1)*4 + (l15&3)
          int pc = nn + wn * 64 + (n >> 1) * 32 + (l15 >> 2) * 8 + (n & 1) * 4 + (l15 & 3);
          V[(size_t)(bh * 128 + cr) * 4096 + pc] = f2h(acc[m][n][j] + bias);
        }
      }
  }
}

// ---------- dilated 3x3 conv sum(SiLU) -> Q[bh][n][d] ----------
__global__ __launch_bounds__(256, 2) void k_conv_q(
    const char* __restrict__ xpad, const unsigned short* __restrict__ Wq,
    const float* __restrict__ qb, unsigned short* __restrict__ Q) {
  extern __shared__ char sm[];
  char* Bs = sm;               // [3 kw][128 co][64 ci] f16 = 49152
  char* As = sm + 49152;       // 3 x [74 w][64 ci] f16 (pitch 10240)
  int t = threadIdx.x, lane = t & 63, wid = t >> 6, q4 = lane >> 4, l15 = lane & 15;
  int h = blockIdx.x, b = blockIdx.y, ch2 = blockIdx.z;
  int co0 = ch2 * 128;
  int wm = wid & 1, wn = wid >> 1;
  const int dil[3] = {1, 3, 5};
  f32x4 accd[3][2][4] = {};
  for (int kh = 0; kh < 3; kh++) {
    for (int c = 0; c < 4; c++) {
      __syncthreads();
      const char* wq_base = (const char*)Wq + kh * 3 * 131072 + co0 * 512 + c * 128;
      for (int ch = wid * 1024; ch < 49152; ch += 4096) {
        int o = ch + lane * 16;
        int kw = o >> 14;
        int r = (o >> 7) & 127;
        int col = (o & 127) ^ ((r & 7) << 4);
        gld_lds16(Bs + ch, wq_base + kw * 131072 + r * 512 + col);
      }
#pragma unroll
      for (int di = 0; di < 3; di++) {
        int pr = h + (kh - 1) * dil[di] + 5;             // always in [0,74)
        const char* g = xpad + (size_t)((b * 74 + pr) * 74) * 512 + c * 128;
        char* Ad = As + di * 10240;
        for (int ch = wid * 1024; ch < 9472; ch += 4096) {
          int o = ch + lane * 16;
          if (o < 9472) {
            int r = o >> 7;
            int col = (o & 127) ^ ((r & 7) << 4);
            gld_lds16(Ad + ch, g + r * 512 + col);
          }
        }
      }
      asm volatile("s_waitcnt vmcnt(0)" ::: "memory");
      __syncthreads();
#pragma unroll
      for (int di = 0; di < 3; di++) {
        int d = dil[di];
        const char* Ad = As + di * 10240;
#pragma unroll
        for (int kw = 0; kw < 3; kw++) {
          int dw = (kw - 1) * d + 5;
          f16x8 af[2][2], bf[4][2];
#pragma unroll
          for (int m = 0; m < 2; m++)
#pragma unroll
            for (int kt = 0; kt < 2; kt++) {
              int wp = wm * 32 + m * 16 + l15 + dw;      // [0,73]
              af[m][kt] = *(const f16x8*)(Ad + ((wp * 128 + kt * 64 + q4 * 16) ^ ((wp & 7) << 4)));
            }
#pragma unroll
          for (int n = 0; n < 4; n++)
#pragma unroll
            for (int kt = 0; kt < 2; kt++) {
              int rc = wn * 64 + n * 16 + l15;
              bf[n][kt] = *(const f16x8*)(Bs + kw * 16384 + ((rc * 128 + kt * 64 + q4 * 16) ^ ((rc & 7) << 4)));
            }
#pragma unroll
          for (int m = 0; m < 2; m++)
#pragma unroll
            for (int n = 0; n < 4; n++)
#pragma unroll
              for (int kt = 0; kt < 2; kt++)
                accd[di][m][n] = __builtin_amdgcn_mfma_f32_16x16x32_f16(af[m][kt], bf[n][kt], accd[di][m][n], 0, 0, 0);
        }
      }
    }
  }
  const float LOG2E = 1.4426950408889634f;
  const float QSCALE = 0.12751879523176862f;  // log2e / sqrt(128)
#pragma unroll
  for (int n = 0; n < 4; n++) {
    float bias = qb[co0 + wn * 64 + n * 16 + l15];
#pragma unroll
    for (int m = 0; m < 2; m++)
#pragma unroll
      for (int j = 0; j < 4; j++) {
        float s = 0.f;
#pragma unroll
        for (int di = 0; di < 3; di++) {
          float v = accd[di][m][n][j] + bias;
          s += v * v_rcp(1.0f + v_exp2(-v * LOG2E));     // SiLU
        }
        int px = wm * 32 + m * 16 + q4 * 4 + j;
        int dd = wn * 64 + n * 16 + l15;
        int npix = h * 64 + px;
        Q[((size_t)(b * 2 + ch2) * 4096 + npix) * 128 + dd] = f2h(s * QSCALE);
      }
  }
}

// ---------- flash attention, KV-split in 2 halves: grid (32, 8, 2), 2 blocks/CU ----------
// P stays in registers: V global layout is m-permuted so the S^T C-layout IS a
// valid PV B-fragment (slot bijection g(q4,e) = (e>>2)*16 + q4*4 + (e&3)).
// half 0: writes unnormalized O (f32) to out + (m,l) to mlbuf
// half 1: writes normalized O (f16) to o1buf + (m,l) to mlbuf
__global__ __launch_bounds__(256, 2) void k_attn(
    const unsigned short* __restrict__ Q, const unsigned short* __restrict__ K,
    const unsigned short* __restrict__ V, float* __restrict__ out,
    unsigned short* __restrict__ o1buf, float* __restrict__ mlbuf) {
  extern __shared__ char sm[];
  char* K0 = sm;                         // [64m][128d] 16KB each, swz16
  char* K1 = sm + 16384;
  char* V0 = sm + 32768;                 // [128d][64s] 16KB each, swz8
  char* V1 = sm + 49152;
  int t = threadIdx.x, lane = t & 63, wid = t >> 6, q4 = lane >> 4, l15 = lane & 15;
  int nb = blockIdx.x, bh = blockIdx.y, half = blockIdx.z;
  int b = bh >> 1, hh = bh & 1;
  int n0 = nb * 128;
  const char* Qg = (const char*)(Q + ((size_t)bh * 4096 + n0) * 128);
  const char* Kg = (const char*)(K + (size_t)bh * 4096 * 128) + half * 524288;   // 32 tiles * 16KB
  const char* Vg = (const char*)(V + (size_t)bh * 128 * 4096) + half * 4096;     // 2048 m * 2B
  // Q fragments direct from global (read once; no LDS staging)
  f16x8 qf[2][4];
#pragma unroll
  for (int nt = 0; nt < 2; nt++)
#pragma unroll
    for (int kt = 0; kt < 4; kt++) {
      int rn = wid * 32 + nt * 16 + l15;
      qf[nt][kt] = *(const f16x8*)(Qg + (size_t)rn * 256 + kt * 64 + q4 * 16);
    }
  // stage first K/V tile of this half
  for (int ch = wid * 1024; ch < 16384; ch += 4096) {
    int o = ch + lane * 16;
    gld_lds16(K0 + ch, Kg + (o ^ (((o >> 8) & 15) << 4)));
  }
  for (int ch = wid * 1024; ch < 16384; ch += 4096) {
    int o = ch + lane * 16;
    int dd = o >> 7;
    int col = (o & 127) ^ ((dd & 7) << 4);
    gld_lds16(V0 + ch, Vg + dd * 8192 + col);
  }
  asm volatile("s_waitcnt vmcnt(0)" ::: "memory");
  __syncthreads();
  f32x4 Ofr[8][2] = {};                  // O^T frags: [d-tile][n-tile], col n = l15
  float mrun[2] = {-3e38f, -3e38f};
  float lrun[2] = {0.f, 0.f};
  for (int it = 0; it < 32; it++) {
    char* Kc = (it & 1) ? K1 : K0;
    char* Vc = (it & 1) ? V1 : V0;
    if (it < 31) {                       // prefetch next tile into other buffer
      char* Kn = (it & 1) ? K0 : K1;
      char* Vn = (it & 1) ? V0 : V1;
      const char* kg = Kg + (size_t)(it + 1) * 16384;
      for (int ch = wid * 1024; ch < 16384; ch += 4096) {
        int o = ch + lane * 16;
        gld_lds16(Kn + ch, kg + (o ^ (((o >> 8) & 15) << 4)));
      }
      const char* vg = Vg + (it + 1) * 128;
      for (int ch = wid * 1024; ch < 16384; ch += 4096) {
        int o = ch + lane * 16;
        int dd = o >> 7;
        int col = (o & 127) ^ ((dd & 7) << 4);
        gld_lds16(Vn + ch, vg + dd * 8192 + col);
      }
    }
    // S^T[m][n] = sum_d K[m][d] Q[n][d]   (swapped operands: softmax state is per-column n = l15)
    f32x4 sT[4][2] = {};
#pragma unroll
    for (int kt = 0; kt < 4; kt++) {
      f16x8 kf[4];
#pragma unroll
      for (int mt = 0; mt < 4; mt++) {
        int rm = mt * 16 + l15;
        kf[mt] = *(const f16x8*)(Kc + ((rm * 256 + kt * 64 + q4 * 16) ^ ((rm & 15) << 4)));
      }
      __builtin_amdgcn_s_setprio(1);
#pragma unroll
      for (int mt = 0; mt < 4; mt++)
#pragma unroll
        for (int nt = 0; nt < 2; nt++)
          sT[mt][nt] = __builtin_amdgcn_mfma_f32_16x16x32_f16(kf[mt], qf[nt][kt], sT[mt][nt], 0, 0, 0);
      __builtin_amdgcn_s_setprio(0);
    }
    // online softmax over m (rows), defer-max rescale (threshold 8); P packed to regs
    unsigned U[2][4][2];
#pragma unroll
    for (int nt = 0; nt < 2; nt++) {
      float mx = sT[0][nt][0];
#pragma unroll
      for (int mt = 0; mt < 4; mt++)
#pragma unroll
        for (int j = 0; j < 4; j++) mx = fmaxf(mx, sT[mt][nt][j]);
      mx = fmaxf(mx, __shfl_xor(mx, 16));
      mx = fmaxf(mx, __shfl_xor(mx, 32));
      float mn = mrun[nt];
      if (!__all(mx - mn <= 8.f)) {      // rare: real max growth -> rescale
        mn = fmaxf(mrun[nt], mx);
        float al = v_exp2(mrun[nt] - mn);
        mrun[nt] = mn;
        lrun[nt] *= al;
#pragma unroll
        for (int dt = 0; dt < 8; dt++) Ofr[dt][nt] *= al;
      }
      float rs = 0.f;
#pragma unroll
      for (int mt = 0; mt < 4; mt++) {
        float p0 = v_exp2(sT[mt][nt][0] - mn);
        float p1 = v_exp2(sT[mt][nt][1] - mn);
        float p2 = v_exp2(sT[mt][nt][2] - mn);
        float p3 = v_exp2(sT[mt][nt][3] - mn);
        rs += (p0 + p1) + (p2 + p3);
        U[nt][mt][0] = pk2h(p0, p1);
        U[nt][mt][1] = pk2h(p2, p3);
      }
      rs += __shfl_xor(rs, 16);
      rs += __shfl_xor(rs, 32);
      lrun[nt] += rs;
    }
    // O^T += V * P.  pf is lane-local: slot (q4,e) <-> m = kt*32 + (e>>2)*16 + q4*4 + (e&3),
    // matching V's permuted storage s = kt*32 + q4*8 + e.
#pragma unroll
    for (int kt = 0; kt < 2; kt++) {
      f16x8 pf[2];
#pragma unroll
      for (int nt = 0; nt < 2; nt++) {
        uint4 fr;
        fr.x = U[nt][2 * kt][0];
        fr.y = U[nt][2 * kt][1];
        fr.z = U[nt][2 * kt + 1][0];
        fr.w = U[nt][2 * kt + 1][1];
        pf[nt] = __builtin_bit_cast(f16x8, fr);
      }
      f16x8 vf[8];
#pragma unroll
      for (int dt = 0; dt < 8; dt++) {
        int rd = dt * 16 + l15;
        vf[dt] = *(const f16x8*)(Vc + ((rd * 128 + kt * 64 + q4 * 16) ^ ((rd & 7) << 4)));
      }
      __builtin_amdgcn_s_setprio(1);
#pragma unroll
      for (int dt = 0; dt < 8; dt++)
#pragma unroll
        for (int nt = 0; nt < 2; nt++)
          Ofr[dt][nt] = __builtin_amdgcn_mfma_f32_16x16x32_f16(vf[dt], pf[nt], Ofr[dt][nt], 0, 0, 0);
      __builtin_amdgcn_s_setprio(0);
    }
    __syncthreads();
  }
  // write (m,l) per q-column
  if (q4 == 0) {
#pragma unroll
    for (int nt = 0; nt < 2; nt++) {
      int n = n0 + wid * 32 + nt * 16 + l15;
      float2 ml;
      ml.x = mrun[nt];
      ml.y = lrun[nt];
      *(float2*)(mlbuf + ((size_t)(half * 8 + bh) * 4096 + n) * 2) = ml;
    }
  }
  if (half == 0) {
    float* og = out + (size_t)(b * 256 + hh * 128) * 4096 + n0 + wid * 32;
#pragma unroll
    for (int dt = 0; dt < 8; dt++)
#pragma unroll
      for (int nt = 0; nt < 2; nt++)
#pragma unroll
        for (int j = 0; j < 4; j++) {
          int dd = dt * 16 + q4 * 4 + j;
          og[(size_t)dd * 4096 + nt * 16 + l15] = Ofr[dt][nt][j];
        }
  } else {
    float li[2] = {v_rcp(lrun[0]), v_rcp(lrun[1])};
    unsigned short* og = o1buf + (size_t)bh * 128 * 4096 + n0 + wid * 32;
#pragma unroll
    for (int dt = 0; dt < 8; dt++)
#pragma unroll
      for (int nt = 0; nt < 2; nt++)
#pragma unroll
        for (int j = 0; j < 4; j++) {
          int dd = dt * 16 + q4 * 4 + j;
          og[(size_t)dd * 4096 + nt * 16 + l15] = f2h(Ofr[dt][nt][j] * li[nt]);
        }
  }
}

// ---------- combine the two KV halves (in-place on out) ----------
__global__ __launch_bounds__(256) void k_combine(
    float* __restrict__ out, const unsigned short* __restrict__ o1,
    const float* __restrict__ ml) {
  int tid = blockIdx.x * 256 + threadIdx.x;    // bits: [0:11]=n, [12:14]=dg, [15:17]=bh
  int n = tid & 4095, dg = (tid >> 12) & 7, bh = tid >> 15;
  float2 ml0 = *(const float2*)(ml + ((size_t)bh * 4096 + n) * 2);
  float2 ml1 = *(const float2*)(ml + ((size_t)(8 + bh) * 4096 + n) * 2);
  float ms = fmaxf(ml0.x, ml1.x);
  float a0 = v_exp2(ml0.x - ms);
  float w1 = ml1.y * v_exp2(ml1.x - ms);
  float inv = 1.f / (ml0.y * a0 + w1);
  size_t ob = ((size_t)((bh >> 1) * 256 + (bh & 1) * 128 + dg * 16)) * 4096 + n;
  size_t o1b = ((size_t)(bh * 128 + dg * 16)) * 4096 + n;
#pragma unroll 4
  for (int j = 0; j < 16; j++) {
    float v0 = out[ob + (size_t)j * 4096];
    float v1 = h2f(o1[o1b + (size_t)j * 4096]);
    out[ob + (size_t)j * 4096] = (v0 * a0 + v1 * w1) * inv;
  }
}

extern "C" void kernel_launch(void* const* d_in, const int* in_sizes, int n_in,
                              void* d_out, int out_size, void* d_ws, size_t ws_size,
                              hipStream_t stream) {
  (void)in_sizes; (void)n_in; (void)out_size;
  const float* x  = (const float*)d_in[0];
  const float* qw = (const float*)d_in[1];
  const float* qb = (const float*)d_in[2];
  const float* kw = (const float*)d_in[3];
  const float* kb = (const float*)d_in[4];
  const float* vw = (const float*)d_in[5];
  const float* vb = (const float*)d_in[6];
  char* ws = (char*)d_ws;
  if (ws_size < 37822464) return;
  char* xpad = ws;
  unsigned short* Wq = (unsigned short*)(ws + 11214848);
  unsigned short* Wk = (unsigned short*)(ws + 12394496);
  unsigned short* Wv = (unsigned short*)(ws + 12525568);
  unsigned short* Qb = (unsigned short*)(ws + 12656640);
  unsigned short* Kb = (unsigned short*)(ws + 21045248);
  unsigned short* Vb = (unsigned short*)(ws + 29433856);
  unsigned short* O1 = (unsigned short*)ws;            // reuse xpad after convs (8.4MB)
  float* ML = (float*)(ws + 11214848);                 // reuse Wq after convs (512KB)
  hipMemsetAsync(xpad, 0, 11214848, stream);
  k_prep_x<<<dim3(64, 4), dim3(256), 0, stream>>>(x, xpad);
  k_prep_w<<<dim3(256), dim3(256), 0, stream>>>(qw, kw, vw, Wq, Wk, Wv);
  k_conv_kv<<<dim3(128, 2, 2), dim3(256), 0, stream>>>(xpad, Wk, Wv, kb, vb, Kb, Vb);
  k_conv_q<<<dim3(64, 4, 2), dim3(256), 79872, stream>>>(xpad, Wq, qb, Qb);
  k_attn<<<dim3(32, 8, 2), dim3(256), 65536, stream>>>(Qb, Kb, Vb, (float*)d_out, O1, ML);
  k_combine<<<dim3(1024), dim3(256), 0, stream>>>((float*)d_out, O1, ML);
}